// Round 2
// baseline (4325.409 us; speedup 1.0000x reference)
//
#include <hip/hip_runtime.h>
#include <hip/hip_bf16.h>

#define N_NODES 100000
#define N_EDGES 800000
#define D_IN 100
#define D_HID 100
#define N_CLS 16

#define TN 64        // nodes per block in node kernel
#define KTOT 200     // concat K (mean || x)
#define STR 204      // padded LDS stride (204%32=12 -> <=2-way bank aliasing, free per m136)

// ---------------- Kernel 1: edge scatter (atomic segment-sum) ----------------
// 2D grid: blockIdx.y = float4 chunk (0..24), blockIdx.x*256+tid = edge.
// Every lane active; edge-index loads coalesced; chunk 0 also does degree.
__global__ __launch_bounds__(256) void sage_scatter(
    const int* __restrict__ ei, const float* __restrict__ x,
    float* __restrict__ agg, float* __restrict__ deg)
{
    const int e = blockIdx.x * 256 + threadIdx.x;
    if (e >= N_EDGES) return;
    const int c = blockIdx.y;                       // 0..24
    const int src = ei[e];
    const int dst = ei[N_EDGES + e];
    const float4 v = *reinterpret_cast<const float4*>(x + (long)src * D_IN + c * 4);
    float* p = agg + (long)dst * D_IN + c * 4;
    unsafeAtomicAdd(p + 0, v.x);
    unsafeAtomicAdd(p + 1, v.y);
    unsafeAtomicAdd(p + 2, v.z);
    unsafeAtomicAdd(p + 3, v.w);
    if (c == 0) unsafeAtomicAdd(deg + dst, 1.0f);
}

// ---------------- Kernel 2: fused node update -------------------------------
// out = relu((agg/deg)@Wl^T + x@Wr^T + bl) @ Wc^T + bc
// GEMM view: A=[TN][200] (mean||x) in LDS, W=[100(+12 pad)][200] in LDS.
// 256 threads = 16 node-groups x 16 out-groups; thread tile = 4 nodes x 7 outs.
__global__ __launch_bounds__(256, 1) void sage_node(
    const float* __restrict__ x, const float* __restrict__ agg,
    const float* __restrict__ deg,
    const float* __restrict__ Wl, const float* __restrict__ bl,
    const float* __restrict__ Wr, const float* __restrict__ Wc,
    const float* __restrict__ bc, float* __restrict__ out)
{
    __shared__ float w_lds[112 * STR];   // rows 100..111 zero-padded
    __shared__ float a_lds[TN * STR];
    __shared__ float wc_lds[16 * 100];
    __shared__ float bl_lds[112];
    __shared__ float bc_lds[16];

    const int tid = threadIdx.x;
    const int node0 = blockIdx.x * TN;

    // ---- stage weights: w_lds[o][k] = k<100 ? Wl[o][k] : Wr[o][k-100]
    for (int idx = tid; idx < 112 * 50; idx += 256) {
        const int o = idx / 50, c = idx - o * 50;
        float4 v = make_float4(0.f, 0.f, 0.f, 0.f);
        if (o < 100) {
            if (c < 25) v = *reinterpret_cast<const float4*>(Wl + o * 100 + c * 4);
            else        v = *reinterpret_cast<const float4*>(Wr + o * 100 + (c - 25) * 4);
        }
        *reinterpret_cast<float4*>(w_lds + o * STR + c * 4) = v;
    }
    for (int idx = tid; idx < 16 * 25; idx += 256) {
        *reinterpret_cast<float4*>(wc_lds + idx * 4) =
            *reinterpret_cast<const float4*>(Wc + idx * 4);
    }
    if (tid < 112) bl_lds[tid] = (tid < 100) ? bl[tid] : 0.0f;
    if (tid < 16)  bc_lds[tid] = bc[tid];

    // ---- stage A: a_lds[n][k] = k<100 ? agg[node][k]/max(deg,1) : x[node][k-100]
    for (int idx = tid; idx < TN * 50; idx += 256) {
        const int n = idx / 50, c = idx - n * 50;
        const int node = node0 + n;
        float4 v = make_float4(0.f, 0.f, 0.f, 0.f);
        if (node < N_NODES) {
            if (c < 25) {
                const float inv = 1.0f / fmaxf(deg[node], 1.0f);
                v = *reinterpret_cast<const float4*>(agg + (long)node * D_IN + c * 4);
                v.x *= inv; v.y *= inv; v.z *= inv; v.w *= inv;
            } else {
                v = *reinterpret_cast<const float4*>(x + (long)node * D_IN + (c - 25) * 4);
            }
        }
        *reinterpret_cast<float4*>(a_lds + n * STR + c * 4) = v;
    }
    __syncthreads();

    // ---- main loop: 4 nodes x 7 outputs per thread
    const int g_n = tid >> 4;   // 0..15 -> nodes g_n*4 .. +3
    const int g_o = tid & 15;   // 0..15 -> outputs g_o + 16j, j=0..6
    float acc[4][7];
    #pragma unroll
    for (int n = 0; n < 4; ++n)
        #pragma unroll
        for (int j = 0; j < 7; ++j) acc[n][j] = 0.0f;

    const float* aP = a_lds + (g_n * 4) * STR;
    const float* wP = w_lds + g_o * STR;

    for (int k = 0; k < KTOT; k += 4) {
        float4 a4[4], w4[7];
        #pragma unroll
        for (int n = 0; n < 4; ++n)
            a4[n] = *reinterpret_cast<const float4*>(aP + n * STR + k);
        #pragma unroll
        for (int j = 0; j < 7; ++j)
            w4[j] = *reinterpret_cast<const float4*>(wP + j * 16 * STR + k);
        #pragma unroll
        for (int n = 0; n < 4; ++n)
            #pragma unroll
            for (int j = 0; j < 7; ++j)
                acc[n][j] += a4[n].x * w4[j].x + a4[n].y * w4[j].y
                           + a4[n].z * w4[j].z + a4[n].w * w4[j].w;
    }
    __syncthreads();   // all reads of a_lds complete

    // ---- h = relu(acc + bl) written back into a_lds (reused as h-tile)
    #pragma unroll
    for (int n = 0; n < 4; ++n) {
        const int node_l = g_n * 4 + n;
        #pragma unroll
        for (int j = 0; j < 7; ++j) {
            const int o = g_o + 16 * j;            // may be 100..111 (pad rows -> h=0)
            const float h = fmaxf(acc[n][j] + bl_lds[o], 0.0f);
            a_lds[node_l * STR + o] = h;
        }
    }
    __syncthreads();

    // ---- classifier: 1 thread = (node, 4 classes)
    {
        const int node_l = tid >> 2;          // 0..63
        const int cg = (tid & 3) * 4;         // 0,4,8,12
        float4 o4 = make_float4(bc_lds[cg], bc_lds[cg + 1], bc_lds[cg + 2], bc_lds[cg + 3]);
        const float* hP = a_lds + node_l * STR;
        for (int o = 0; o < 100; o += 4) {
            const float4 h4 = *reinterpret_cast<const float4*>(hP + o);
            #pragma unroll
            for (int q = 0; q < 4; ++q) {
                const float4 w = *reinterpret_cast<const float4*>(wc_lds + (cg + q) * 100 + o);
                (&o4.x)[q] += h4.x * w.x + h4.y * w.y + h4.z * w.z + h4.w * w.w;
            }
        }
        const int node = node0 + node_l;
        if (node < N_NODES)
            *reinterpret_cast<float4*>(out + (long)node * N_CLS + cg) = o4;
    }
}

extern "C" void kernel_launch(void* const* d_in, const int* in_sizes, int n_in,
                              void* d_out, int out_size, void* d_ws, size_t ws_size,
                              hipStream_t stream) {
    const float* x  = (const float*)d_in[0];
    const int*   ei = (const int*)d_in[1];
    const float* Wl = (const float*)d_in[2];
    const float* bl = (const float*)d_in[3];
    const float* Wr = (const float*)d_in[4];
    const float* Wc = (const float*)d_in[5];
    const float* bc = (const float*)d_in[6];
    float* out = (float*)d_out;

    float* agg = (float*)d_ws;                           // [N_NODES][D_IN]
    float* deg = agg + (size_t)N_NODES * D_IN;           // [N_NODES]

    hipMemsetAsync(d_ws, 0, ((size_t)N_NODES * D_IN + N_NODES) * sizeof(float), stream);

    dim3 sgrid((N_EDGES + 255) / 256, 25);
    sage_scatter<<<sgrid, 256, 0, stream>>>(ei, x, agg, deg);

    sage_node<<<(N_NODES + TN - 1) / TN, 256, 0, stream>>>(
        x, agg, deg, Wl, bl, Wr, Wc, bc, out);
}

// Round 3
// 778.128 us; speedup vs baseline: 5.5587x; 5.5587x over previous
//
#include <hip/hip_runtime.h>
#include <hip/hip_bf16.h>

#define N_NODES 100000
#define N_EDGES 800000
#define D_IN 100
#define D_HID 100
#define N_CLS 16

#define TN 64        // nodes per block in node kernel
#define KTOT 200     // concat K (mean || x)
#define STR 204      // padded LDS stride (204%32=12 -> <=2-way bank aliasing, free per m136)
#define NPT 98       // scan: elements per thread (1024*98 >= 100000)

// ---------------- Kernel 1: degree histogram (int atomics) ------------------
__global__ __launch_bounds__(256) void hist_k(const int* __restrict__ ei,
                                              int* __restrict__ cnt)
{
    const int e = blockIdx.x * 256 + threadIdx.x;
    if (e < N_EDGES) atomicAdd(&cnt[ei[N_EDGES + e]], 1);
}

// ---------------- Kernel 2: exclusive scan of counts (single block) ---------
__global__ __launch_bounds__(1024) void scan_counts(const int* __restrict__ cnt,
                                                    int* __restrict__ rowptr,
                                                    int* __restrict__ wofs)
{
    __shared__ int sums[1024];
    const int t = threadIdx.x;
    const int base = t * NPT;
    int s = 0;
    for (int i = 0; i < NPT; ++i) {
        const int idx = base + i;
        if (idx < N_NODES) s += cnt[idx];
    }
    sums[t] = s;
    __syncthreads();
    // Hillis-Steele inclusive scan
    for (int d = 1; d < 1024; d <<= 1) {
        const int v = sums[t];
        const int add = (t >= d) ? sums[t - d] : 0;
        __syncthreads();
        sums[t] = v + add;
        __syncthreads();
    }
    int prefix = (t > 0) ? sums[t - 1] : 0;
    for (int i = 0; i < NPT; ++i) {
        const int idx = base + i;
        if (idx < N_NODES) {
            rowptr[idx] = prefix;
            wofs[idx] = prefix;
            prefix += cnt[idx];
        }
    }
    if (t == 1023) rowptr[N_NODES] = sums[1023];
}

// ---------------- Kernel 3: fill CSR adjacency (permutation scatter) --------
__global__ __launch_bounds__(256) void fill_csr(const int* __restrict__ ei,
                                                int* __restrict__ wofs,
                                                int* __restrict__ esrc)
{
    const int e = blockIdx.x * 256 + threadIdx.x;
    if (e >= N_EDGES) return;
    const int src = ei[e];
    const int dst = ei[N_EDGES + e];
    const int pos = atomicAdd(&wofs[dst], 1);
    esrc[pos] = src;
}

// ---------------- Kernel 4: fused gather-mean + node update -----------------
// out = relu(mean@Wl^T + x@Wr^T + bl) @ Wc^T + bc
// A=[TN][200] (mean||x) in LDS (mean gathered from CSR), W=[112pad][200] in LDS.
// 512 threads: GEMM tile = 2 nodes x 7 outs per thread. 8 waves = 2/SIMD.
__global__ __launch_bounds__(512, 1) void sage_node(
    const float* __restrict__ x,
    const int* __restrict__ rowptr, const int* __restrict__ esrc,
    const float* __restrict__ Wl, const float* __restrict__ bl,
    const float* __restrict__ Wr, const float* __restrict__ Wc,
    const float* __restrict__ bc, float* __restrict__ out)
{
    __shared__ float w_lds[112 * STR];   // rows 100..111 zero-padded
    __shared__ float a_lds[TN * STR];
    __shared__ float wc_lds[16 * 100];
    __shared__ float bl_lds[112];
    __shared__ float bc_lds[16];

    const int tid = threadIdx.x;
    const int node0 = blockIdx.x * TN;

    // ---- stage weights: w_lds[o][k] = k<100 ? Wl[o][k] : Wr[o][k-100]
    for (int idx = tid; idx < 112 * 50; idx += 512) {
        const int o = idx / 50, c = idx - o * 50;
        float4 v = make_float4(0.f, 0.f, 0.f, 0.f);
        if (o < 100) {
            if (c < 25) v = *reinterpret_cast<const float4*>(Wl + o * 100 + c * 4);
            else        v = *reinterpret_cast<const float4*>(Wr + o * 100 + (c - 25) * 4);
        }
        *reinterpret_cast<float4*>(w_lds + o * STR + c * 4) = v;
    }
    for (int idx = tid; idx < 16 * 25; idx += 512) {
        *reinterpret_cast<float4*>(wc_lds + idx * 4) =
            *reinterpret_cast<const float4*>(Wc + idx * 4);
    }
    if (tid < 112) bl_lds[tid] = (tid < 100) ? bl[tid] : 0.0f;
    if (tid < 16)  bc_lds[tid] = bc[tid];

    // ---- stage A right half: a_lds[n][100+k] = x[node][k]
    for (int idx = tid; idx < TN * 25; idx += 512) {
        const int n = idx / 25, c = idx - n * 25;
        const int node = node0 + n;
        float4 v = make_float4(0.f, 0.f, 0.f, 0.f);
        if (node < N_NODES)
            v = *reinterpret_cast<const float4*>(x + (long)node * D_IN + c * 4);
        *reinterpret_cast<float4*>(a_lds + n * STR + 100 + c * 4) = v;
    }

    // ---- stage A left half via CSR gather: a_lds[n][k] = mean_{src in N(node)} x[src][k]
    // 16 half-waves x 4 nodes each; lanes 0..24 own one float4 chunk.
    {
        const int hw = tid >> 5;        // 0..15
        const int l32 = tid & 31;       // 0..31
        for (int nn = 0; nn < 4; ++nn) {
            const int n = hw * 4 + nn;
            const int node = node0 + n;
            if (node >= N_NODES) break;
            const int r0 = rowptr[node];
            const int r1 = rowptr[node + 1];
            if (l32 < 25) {
                float4 acc = make_float4(0.f, 0.f, 0.f, 0.f);
                for (int j = r0; j < r1; ++j) {
                    const int src = esrc[j];
                    const float4 v = *reinterpret_cast<const float4*>(
                        x + (long)src * D_IN + l32 * 4);
                    acc.x += v.x; acc.y += v.y; acc.z += v.z; acc.w += v.w;
                }
                const float inv = 1.0f / fmaxf((float)(r1 - r0), 1.0f);
                acc.x *= inv; acc.y *= inv; acc.z *= inv; acc.w *= inv;
                *reinterpret_cast<float4*>(a_lds + n * STR + l32 * 4) = acc;
            }
        }
    }
    __syncthreads();

    // ---- main GEMM: 2 nodes x 7 outputs per thread
    const int g_n = tid >> 4;   // 0..31 -> nodes g_n*2, g_n*2+1
    const int g_o = tid & 15;   // 0..15 -> outputs g_o + 16j, j=0..6
    float acc[2][7];
    #pragma unroll
    for (int n = 0; n < 2; ++n)
        #pragma unroll
        for (int j = 0; j < 7; ++j) acc[n][j] = 0.0f;

    const float* aP = a_lds + (g_n * 2) * STR;
    const float* wP = w_lds + g_o * STR;

    for (int k = 0; k < KTOT; k += 4) {
        float4 a4[2], w4[7];
        #pragma unroll
        for (int n = 0; n < 2; ++n)
            a4[n] = *reinterpret_cast<const float4*>(aP + n * STR + k);
        #pragma unroll
        for (int j = 0; j < 7; ++j)
            w4[j] = *reinterpret_cast<const float4*>(wP + j * 16 * STR + k);
        #pragma unroll
        for (int n = 0; n < 2; ++n)
            #pragma unroll
            for (int j = 0; j < 7; ++j)
                acc[n][j] += a4[n].x * w4[j].x + a4[n].y * w4[j].y
                           + a4[n].z * w4[j].z + a4[n].w * w4[j].w;
    }
    __syncthreads();   // all reads of a_lds complete

    // ---- h = relu(acc + bl) written back into a_lds (reused as h-tile)
    #pragma unroll
    for (int n = 0; n < 2; ++n) {
        const int node_l = g_n * 2 + n;
        #pragma unroll
        for (int j = 0; j < 7; ++j) {
            const int o = g_o + 16 * j;            // may be 100..111 (pad rows -> h=0)
            const float h = fmaxf(acc[n][j] + bl_lds[o], 0.0f);
            a_lds[node_l * STR + o] = h;
        }
    }
    __syncthreads();

    // ---- classifier: 1 thread = (node, 2 classes)
    {
        const int node_l = tid >> 3;          // 0..63
        const int q = tid & 7;                // class pair: 2q, 2q+1
        float o0 = bc_lds[2 * q], o1 = bc_lds[2 * q + 1];
        const float* hP = a_lds + node_l * STR;
        const float* w0 = wc_lds + (2 * q) * 100;
        const float* w1 = wc_lds + (2 * q + 1) * 100;
        for (int o = 0; o < 100; o += 4) {
            const float4 h4 = *reinterpret_cast<const float4*>(hP + o);
            const float4 a = *reinterpret_cast<const float4*>(w0 + o);
            const float4 b = *reinterpret_cast<const float4*>(w1 + o);
            o0 += h4.x * a.x + h4.y * a.y + h4.z * a.z + h4.w * a.w;
            o1 += h4.x * b.x + h4.y * b.y + h4.z * b.z + h4.w * b.w;
        }
        const int node = node0 + node_l;
        if (node < N_NODES)
            *reinterpret_cast<float2*>(out + (long)node * N_CLS + 2 * q) =
                make_float2(o0, o1);
    }
}

extern "C" void kernel_launch(void* const* d_in, const int* in_sizes, int n_in,
                              void* d_out, int out_size, void* d_ws, size_t ws_size,
                              hipStream_t stream) {
    const float* x  = (const float*)d_in[0];
    const int*   ei = (const int*)d_in[1];
    const float* Wl = (const float*)d_in[2];
    const float* bl = (const float*)d_in[3];
    const float* Wr = (const float*)d_in[4];
    const float* Wc = (const float*)d_in[5];
    const float* bc = (const float*)d_in[6];
    float* out = (float*)d_out;

    // workspace layout (ints): cnt[N], rowptr[N+4], wofs[N], esrc[E]
    int* cnt    = (int*)d_ws;
    int* rowptr = cnt + N_NODES;
    int* wofs   = rowptr + N_NODES + 4;
    int* esrc   = wofs + N_NODES;

    hipMemsetAsync(cnt, 0, N_NODES * sizeof(int), stream);

    hist_k<<<(N_EDGES + 255) / 256, 256, 0, stream>>>(ei, cnt);
    scan_counts<<<1, 1024, 0, stream>>>(cnt, rowptr, wofs);
    fill_csr<<<(N_EDGES + 255) / 256, 256, 0, stream>>>(ei, wofs, esrc);

    sage_node<<<(N_NODES + TN - 1) / TN, 512, 0, stream>>>(
        x, rowptr, esrc, Wl, bl, Wr, Wc, bc, out);
}

// Round 4
// 661.024 us; speedup vs baseline: 6.5435x; 1.1772x over previous
//
#include <hip/hip_runtime.h>
#include <hip/hip_bf16.h>

#define N_NODES 100000
#define N_EDGES 800000
#define D_IN 100
#define D_HID 100
#define N_CLS 16

#define TN 64        // nodes per block in node kernel
#define STR 204      // padded LDS stride
#define NPT 98       // scan: elements per thread (1024*98 >= 100000)

// ---------------- Kernel 1: degree histogram (int atomics) ------------------
__global__ __launch_bounds__(256) void hist_k(const int* __restrict__ ei,
                                              int* __restrict__ cnt)
{
    const int e = blockIdx.x * 256 + threadIdx.x;
    if (e < N_EDGES) atomicAdd(&cnt[ei[N_EDGES + e]], 1);
}

// ---------------- Kernel 2: exclusive scan of counts (single block) ---------
__global__ __launch_bounds__(1024) void scan_counts(const int* __restrict__ cnt,
                                                    int* __restrict__ rowptr,
                                                    int* __restrict__ wofs)
{
    __shared__ int sums[1024];
    const int t = threadIdx.x;
    const int base = t * NPT;
    int s = 0;
    for (int i = 0; i < NPT; ++i) {
        const int idx = base + i;
        if (idx < N_NODES) s += cnt[idx];
    }
    sums[t] = s;
    __syncthreads();
    for (int d = 1; d < 1024; d <<= 1) {
        const int v = sums[t];
        const int add = (t >= d) ? sums[t - d] : 0;
        __syncthreads();
        sums[t] = v + add;
        __syncthreads();
    }
    int prefix = (t > 0) ? sums[t - 1] : 0;
    for (int i = 0; i < NPT; ++i) {
        const int idx = base + i;
        if (idx < N_NODES) {
            rowptr[idx] = prefix;
            wofs[idx] = prefix;
            prefix += cnt[idx];
        }
    }
    if (t == 1023) rowptr[N_NODES] = sums[1023];
}

// ---------------- Kernel 3: fill CSR adjacency (permutation scatter) --------
__global__ __launch_bounds__(256) void fill_csr(const int* __restrict__ ei,
                                                int* __restrict__ wofs,
                                                int* __restrict__ esrc)
{
    const int e = blockIdx.x * 256 + threadIdx.x;
    if (e >= N_EDGES) return;
    const int src = ei[e];
    const int dst = ei[N_EDGES + e];
    const int pos = atomicAdd(&wofs[dst], 1);
    esrc[pos] = src;
}

// ---------------- Kernel 4: gather-mean (high occupancy, no LDS) ------------
// 32 lanes per node: edge list loaded coalesced 32-wide, src broadcast by shfl,
// lanes 0..24 accumulate one float4 chunk of x[src].
__global__ __launch_bounds__(256) void gather_mean(
    const float* __restrict__ x, const int* __restrict__ rowptr,
    const int* __restrict__ esrc, float* __restrict__ mean)
{
    const int node = blockIdx.x * 8 + (threadIdx.x >> 5);
    if (node >= N_NODES) return;
    const int l = threadIdx.x & 31;
    const int r0 = rowptr[node];
    const int deg = rowptr[node + 1] - r0;

    float4 acc = make_float4(0.f, 0.f, 0.f, 0.f);
    for (int base = 0; base < deg; base += 32) {
        int s = 0;
        if (base + l < deg) s = esrc[r0 + base + l];      // coalesced
        const int rem = deg - base;
        const int m = rem < 32 ? rem : 32;
        for (int j = 0; j < m; ++j) {
            const int src = __shfl(s, j, 32);             // register broadcast
            if (l < 25) {
                const float4 v = *reinterpret_cast<const float4*>(
                    x + (long)src * D_IN + l * 4);
                acc.x += v.x; acc.y += v.y; acc.z += v.z; acc.w += v.w;
            }
        }
    }
    if (l < 25) {
        const float inv = 1.0f / fmaxf((float)deg, 1.0f);
        acc.x *= inv; acc.y *= inv; acc.z *= inv; acc.w *= inv;
        *reinterpret_cast<float4*>(mean + (long)node * D_IN + l * 4) = acc;
    }
}

// ---------------- Kernel 5: fused node GEMM + classifier --------------------
// out = relu((mean||x)@[Wl|Wr]^T + bl) @ Wc^T + bc
// 512 threads = 2 k-halves x (16 node-grp x 16 out-grp); tile 4 nodes x 7 outs.
// K-split partials reduced through w_lds space (free after main loop).
__global__ __launch_bounds__(512, 1) void sage_node(
    const float* __restrict__ x, const float* __restrict__ mean,
    const float* __restrict__ Wl, const float* __restrict__ bl,
    const float* __restrict__ Wr, const float* __restrict__ Wc,
    const float* __restrict__ bc, float* __restrict__ out)
{
    __shared__ float w_lds[112 * STR];   // rows 100..111 zero-padded
    __shared__ float a_lds[TN * STR];
    __shared__ float wc_lds[16 * 100];
    __shared__ float bl_lds[112];
    __shared__ float bc_lds[16];

    const int tid = threadIdx.x;
    const int node0 = blockIdx.x * TN;

    // ---- stage weights: w_lds[o][k] = k<100 ? Wl[o][k] : Wr[o][k-100]
    for (int idx = tid; idx < 112 * 50; idx += 512) {
        const int o = idx / 50, c = idx - o * 50;
        float4 v = make_float4(0.f, 0.f, 0.f, 0.f);
        if (o < 100) {
            if (c < 25) v = *reinterpret_cast<const float4*>(Wl + o * 100 + c * 4);
            else        v = *reinterpret_cast<const float4*>(Wr + o * 100 + (c - 25) * 4);
        }
        *reinterpret_cast<float4*>(w_lds + o * STR + c * 4) = v;
    }
    for (int idx = tid; idx < 16 * 25; idx += 512) {
        *reinterpret_cast<float4*>(wc_lds + idx * 4) =
            *reinterpret_cast<const float4*>(Wc + idx * 4);
    }
    if (tid < 112) bl_lds[tid] = (tid < 100) ? bl[tid] : 0.0f;
    if (tid < 16)  bc_lds[tid] = bc[tid];

    // ---- stage A: a_lds[n][k] = k<100 ? mean[node][k] : x[node][k-100]
    for (int idx = tid; idx < TN * 50; idx += 512) {
        const int n = idx / 50, c = idx - n * 50;
        const int node = node0 + n;
        float4 v = make_float4(0.f, 0.f, 0.f, 0.f);
        if (node < N_NODES) {
            if (c < 25)
                v = *reinterpret_cast<const float4*>(mean + (long)node * D_IN + c * 4);
            else
                v = *reinterpret_cast<const float4*>(x + (long)node * D_IN + (c - 25) * 4);
        }
        *reinterpret_cast<float4*>(a_lds + n * STR + c * 4) = v;
    }
    __syncthreads();

    // ---- main GEMM: k-split halves, 4 nodes x 7 outputs per thread
    const int g   = tid & 255;
    const int kh  = tid >> 8;          // 0 or 1: k in [kh*100, kh*100+100)
    const int g_n = g >> 4;            // 0..15 -> nodes g_n*4 .. +3
    const int g_o = g & 15;            // 0..15 -> outputs g_o + 16j, j=0..6
    float acc[4][7];
    #pragma unroll
    for (int n = 0; n < 4; ++n)
        #pragma unroll
        for (int j = 0; j < 7; ++j) acc[n][j] = 0.0f;

    const float* aP = a_lds + (g_n * 4) * STR + kh * 100;
    const float* wP = w_lds + g_o * STR + kh * 100;

    for (int k = 0; k < 100; k += 4) {
        float4 a4[4], w4[7];
        #pragma unroll
        for (int n = 0; n < 4; ++n)
            a4[n] = *reinterpret_cast<const float4*>(aP + n * STR + k);
        #pragma unroll
        for (int j = 0; j < 7; ++j)
            w4[j] = *reinterpret_cast<const float4*>(wP + j * 16 * STR + k);
        #pragma unroll
        for (int n = 0; n < 4; ++n)
            #pragma unroll
            for (int j = 0; j < 7; ++j)
                acc[n][j] += a4[n].x * w4[j].x + a4[n].y * w4[j].y
                           + a4[n].z * w4[j].z + a4[n].w * w4[j].w;
    }
    __syncthreads();   // w_lds/a_lds reads complete; w_lds space reusable

    // ---- reduce the two k-halves through w_lds (stride 29 = conflict-free)
    float* red = w_lds;
    if (kh == 1) {
        #pragma unroll
        for (int n = 0; n < 4; ++n)
            #pragma unroll
            for (int j = 0; j < 7; ++j)
                red[g * 29 + n * 7 + j] = acc[n][j];
    }
    __syncthreads();

    // ---- h = relu(acc0+acc1+bl) -> a_lds (reused as h-tile)
    if (kh == 0) {
        #pragma unroll
        for (int n = 0; n < 4; ++n) {
            const int node_l = g_n * 4 + n;
            #pragma unroll
            for (int j = 0; j < 7; ++j) {
                const int o = g_o + 16 * j;     // may be 100..111 (pad -> h=0)
                const float h = fmaxf(acc[n][j] + red[g * 29 + n * 7 + j]
                                      + bl_lds[o], 0.0f);
                a_lds[node_l * STR + o] = h;
            }
        }
    }
    __syncthreads();

    // ---- classifier: 1 thread = (node, 2 classes)
    {
        const int node_l = tid >> 3;          // 0..63
        const int q = tid & 7;                // classes 2q, 2q+1
        float o0 = bc_lds[2 * q], o1 = bc_lds[2 * q + 1];
        const float* hP = a_lds + node_l * STR;
        const float* w0 = wc_lds + (2 * q) * 100;
        const float* w1 = wc_lds + (2 * q + 1) * 100;
        for (int o = 0; o < 100; o += 4) {
            const float4 h4 = *reinterpret_cast<const float4*>(hP + o);
            const float4 a = *reinterpret_cast<const float4*>(w0 + o);
            const float4 b = *reinterpret_cast<const float4*>(w1 + o);
            o0 += h4.x * a.x + h4.y * a.y + h4.z * a.z + h4.w * a.w;
            o1 += h4.x * b.x + h4.y * b.y + h4.z * b.z + h4.w * b.w;
        }
        const int node = node0 + node_l;
        if (node < N_NODES)
            *reinterpret_cast<float2*>(out + (long)node * N_CLS + 2 * q) =
                make_float2(o0, o1);
    }
}

extern "C" void kernel_launch(void* const* d_in, const int* in_sizes, int n_in,
                              void* d_out, int out_size, void* d_ws, size_t ws_size,
                              hipStream_t stream) {
    const float* x  = (const float*)d_in[0];
    const int*   ei = (const int*)d_in[1];
    const float* Wl = (const float*)d_in[2];
    const float* bl = (const float*)d_in[3];
    const float* Wr = (const float*)d_in[4];
    const float* Wc = (const float*)d_in[5];
    const float* bc = (const float*)d_in[6];
    float* out = (float*)d_out;

    // ws layout (ints): cnt[N], rowptr[N+4], wofs[N], esrc[E], then mean[N*100] f32
    int* cnt    = (int*)d_ws;
    int* rowptr = cnt + N_NODES;
    int* wofs   = rowptr + N_NODES + 4;
    int* esrc   = wofs + N_NODES;
    float* mean = (float*)(esrc + N_EDGES);   // byte offset 4400016, 16B-aligned

    hipMemsetAsync(cnt, 0, N_NODES * sizeof(int), stream);

    hist_k<<<(N_EDGES + 255) / 256, 256, 0, stream>>>(ei, cnt);
    scan_counts<<<1, 1024, 0, stream>>>(cnt, rowptr, wofs);
    fill_csr<<<(N_EDGES + 255) / 256, 256, 0, stream>>>(ei, wofs, esrc);
    gather_mean<<<(N_NODES + 7) / 8, 256, 0, stream>>>(x, rowptr, esrc, mean);

    sage_node<<<(N_NODES + TN - 1) / TN, 512, 0, stream>>>(
        x, mean, Wl, bl, Wr, Wc, bc, out);
}

// Round 5
// 414.371 us; speedup vs baseline: 10.4385x; 1.5952x over previous
//
#include <hip/hip_runtime.h>
#include <hip/hip_bf16.h>

#define N_NODES 100000
#define N_EDGES 800000
#define D_IN 100
#define D_HID 100
#define N_CLS 16

#define TN 64        // nodes per block in node kernel
#define STR 204      // padded LDS stride
#define SCHUNK 1024  // scan: elements per block
#define SNBLK 98     // ceil(100000/1024)

// ---------------- Kernel 1: degree histogram (int atomics) ------------------
__global__ __launch_bounds__(256) void hist_k(const int* __restrict__ ei,
                                              int* __restrict__ cnt)
{
    const int e = blockIdx.x * 256 + threadIdx.x;
    if (e < N_EDGES) atomicAdd(&cnt[ei[N_EDGES + e]], 1);
}

// ---------------- Scan pass A: per-block chunk sums -------------------------
__global__ __launch_bounds__(256) void scan_a(const int* __restrict__ cnt,
                                              int* __restrict__ bsum)
{
    __shared__ int red[256];
    const int t = threadIdx.x;
    const int base = blockIdx.x * SCHUNK + t * 4;
    int s = 0;
    if (base + 3 < N_NODES) {
        const int4 v = *reinterpret_cast<const int4*>(cnt + base);
        s = v.x + v.y + v.z + v.w;
    } else {
        for (int i = 0; i < 4; ++i)
            if (base + i < N_NODES) s += cnt[base + i];
    }
    red[t] = s;
    __syncthreads();
    for (int d = 128; d > 0; d >>= 1) {
        if (t < d) red[t] += red[t + d];
        __syncthreads();
    }
    if (t == 0) bsum[blockIdx.x] = red[0];
}

// ---------------- Scan pass B: scan the 98 block sums (tiny) ----------------
__global__ __launch_bounds__(128) void scan_b(const int* __restrict__ bsum,
                                              int* __restrict__ boffs,
                                              int* __restrict__ rowptr)
{
    __shared__ int s[128];
    const int t = threadIdx.x;
    const int v = (t < SNBLK) ? bsum[t] : 0;
    s[t] = v;
    __syncthreads();
    for (int d = 1; d < 128; d <<= 1) {
        const int a = s[t];
        const int add = (t >= d) ? s[t - d] : 0;
        __syncthreads();
        s[t] = a + add;
        __syncthreads();
    }
    if (t < SNBLK) boffs[t] = s[t] - v;     // exclusive
    if (t == 127) rowptr[N_NODES] = s[127]; // total (== N_EDGES)
}

// ---------------- Scan pass C: block-local scan + global offset -------------
__global__ __launch_bounds__(256) void scan_c(const int* __restrict__ cnt,
                                              const int* __restrict__ boffs,
                                              int* __restrict__ rowptr,
                                              int* __restrict__ wofs)
{
    __shared__ int red[256];
    const int t = threadIdx.x;
    const int base = blockIdx.x * SCHUNK + t * 4;
    int c0 = 0, c1 = 0, c2 = 0, c3 = 0;
    if (base + 3 < N_NODES) {
        const int4 v = *reinterpret_cast<const int4*>(cnt + base);
        c0 = v.x; c1 = v.y; c2 = v.z; c3 = v.w;
    } else {
        if (base + 0 < N_NODES) c0 = cnt[base + 0];
        if (base + 1 < N_NODES) c1 = cnt[base + 1];
        if (base + 2 < N_NODES) c2 = cnt[base + 2];
        if (base + 3 < N_NODES) c3 = cnt[base + 3];
    }
    const int s = c0 + c1 + c2 + c3;
    red[t] = s;
    __syncthreads();
    for (int d = 1; d < 256; d <<= 1) {       // Hillis-Steele inclusive
        const int a = red[t];
        const int add = (t >= d) ? red[t - d] : 0;
        __syncthreads();
        red[t] = a + add;
        __syncthreads();
    }
    int prefix = boffs[blockIdx.x] + red[t] - s;   // exclusive within grid
    const int c[4] = {c0, c1, c2, c3};
    for (int i = 0; i < 4; ++i) {
        const int idx = base + i;
        if (idx < N_NODES) {
            rowptr[idx] = prefix;
            wofs[idx] = prefix;
            prefix += c[i];
        }
    }
}

// ---------------- Kernel 3: fill CSR adjacency (permutation scatter) --------
__global__ __launch_bounds__(256) void fill_csr(const int* __restrict__ ei,
                                                int* __restrict__ wofs,
                                                int* __restrict__ esrc)
{
    const int e = blockIdx.x * 256 + threadIdx.x;
    if (e >= N_EDGES) return;
    const int src = ei[e];
    const int dst = ei[N_EDGES + e];
    const int pos = atomicAdd(&wofs[dst], 1);
    esrc[pos] = src;
}

// ---------------- Kernel 4: gather-mean (high occupancy, no LDS) ------------
__global__ __launch_bounds__(256) void gather_mean(
    const float* __restrict__ x, const int* __restrict__ rowptr,
    const int* __restrict__ esrc, float* __restrict__ mean)
{
    const int node = blockIdx.x * 8 + (threadIdx.x >> 5);
    if (node >= N_NODES) return;
    const int l = threadIdx.x & 31;
    const int r0 = rowptr[node];
    const int deg = rowptr[node + 1] - r0;

    float4 acc = make_float4(0.f, 0.f, 0.f, 0.f);
    for (int base = 0; base < deg; base += 32) {
        int s = 0;
        if (base + l < deg) s = esrc[r0 + base + l];      // coalesced
        const int rem = deg - base;
        const int m = rem < 32 ? rem : 32;
        for (int j = 0; j < m; ++j) {
            const int src = __shfl(s, j, 32);             // register broadcast
            if (l < 25) {
                const float4 v = *reinterpret_cast<const float4*>(
                    x + (long)src * D_IN + l * 4);
                acc.x += v.x; acc.y += v.y; acc.z += v.z; acc.w += v.w;
            }
        }
    }
    if (l < 25) {
        const float inv = 1.0f / fmaxf((float)deg, 1.0f);
        acc.x *= inv; acc.y *= inv; acc.z *= inv; acc.w *= inv;
        *reinterpret_cast<float4*>(mean + (long)node * D_IN + l * 4) = acc;
    }
}

// ---------------- Kernel 5: fused node GEMM + classifier --------------------
// out = relu((mean||x)@[Wl|Wr]^T + bl) @ Wc^T + bc
// 512 threads = 2 k-halves x (16 node-grp x 16 out-grp); tile 4 nodes x 7 outs.
__global__ __launch_bounds__(512, 1) void sage_node(
    const float* __restrict__ x, const float* __restrict__ mean,
    const float* __restrict__ Wl, const float* __restrict__ bl,
    const float* __restrict__ Wr, const float* __restrict__ Wc,
    const float* __restrict__ bc, float* __restrict__ out)
{
    __shared__ float w_lds[112 * STR];   // rows 100..111 zero-padded
    __shared__ float a_lds[TN * STR];
    __shared__ float wc_lds[16 * 100];
    __shared__ float bl_lds[112];
    __shared__ float bc_lds[16];

    const int tid = threadIdx.x;
    const int node0 = blockIdx.x * TN;

    // ---- stage weights: w_lds[o][k] = k<100 ? Wl[o][k] : Wr[o][k-100]
    for (int idx = tid; idx < 112 * 50; idx += 512) {
        const int o = idx / 50, c = idx - o * 50;
        float4 v = make_float4(0.f, 0.f, 0.f, 0.f);
        if (o < 100) {
            if (c < 25) v = *reinterpret_cast<const float4*>(Wl + o * 100 + c * 4);
            else        v = *reinterpret_cast<const float4*>(Wr + o * 100 + (c - 25) * 4);
        }
        *reinterpret_cast<float4*>(w_lds + o * STR + c * 4) = v;
    }
    for (int idx = tid; idx < 16 * 25; idx += 512) {
        *reinterpret_cast<float4*>(wc_lds + idx * 4) =
            *reinterpret_cast<const float4*>(Wc + idx * 4);
    }
    if (tid < 112) bl_lds[tid] = (tid < 100) ? bl[tid] : 0.0f;
    if (tid < 16)  bc_lds[tid] = bc[tid];

    // ---- stage A: a_lds[n][k] = k<100 ? mean[node][k] : x[node][k-100]
    for (int idx = tid; idx < TN * 50; idx += 512) {
        const int n = idx / 50, c = idx - n * 50;
        const int node = node0 + n;
        float4 v = make_float4(0.f, 0.f, 0.f, 0.f);
        if (node < N_NODES) {
            if (c < 25)
                v = *reinterpret_cast<const float4*>(mean + (long)node * D_IN + c * 4);
            else
                v = *reinterpret_cast<const float4*>(x + (long)node * D_IN + (c - 25) * 4);
        }
        *reinterpret_cast<float4*>(a_lds + n * STR + c * 4) = v;
    }
    __syncthreads();

    // ---- main GEMM: k-split halves, 4 nodes x 7 outputs per thread
    const int g   = tid & 255;
    const int kh  = tid >> 8;          // 0 or 1: k in [kh*100, kh*100+100)
    const int g_n = g >> 4;            // 0..15 -> nodes g_n*4 .. +3
    const int g_o = g & 15;            // 0..15 -> outputs g_o + 16j, j=0..6
    float acc[4][7];
    #pragma unroll
    for (int n = 0; n < 4; ++n)
        #pragma unroll
        for (int j = 0; j < 7; ++j) acc[n][j] = 0.0f;

    const float* aP = a_lds + (g_n * 4) * STR + kh * 100;
    const float* wP = w_lds + g_o * STR + kh * 100;

    for (int k = 0; k < 100; k += 4) {
        float4 a4[4], w4[7];
        #pragma unroll
        for (int n = 0; n < 4; ++n)
            a4[n] = *reinterpret_cast<const float4*>(aP + n * STR + k);
        #pragma unroll
        for (int j = 0; j < 7; ++j)
            w4[j] = *reinterpret_cast<const float4*>(wP + j * 16 * STR + k);
        #pragma unroll
        for (int n = 0; n < 4; ++n)
            #pragma unroll
            for (int j = 0; j < 7; ++j)
                acc[n][j] += a4[n].x * w4[j].x + a4[n].y * w4[j].y
                           + a4[n].z * w4[j].z + a4[n].w * w4[j].w;
    }
    __syncthreads();   // w_lds/a_lds reads complete; w_lds space reusable

    // ---- reduce the two k-halves through w_lds (stride 29 = conflict-free)
    float* red = w_lds;
    if (kh == 1) {
        #pragma unroll
        for (int n = 0; n < 4; ++n)
            #pragma unroll
            for (int j = 0; j < 7; ++j)
                red[g * 29 + n * 7 + j] = acc[n][j];
    }
    __syncthreads();

    // ---- h = relu(acc0+acc1+bl) -> a_lds (reused as h-tile)
    if (kh == 0) {
        #pragma unroll
        for (int n = 0; n < 4; ++n) {
            const int node_l = g_n * 4 + n;
            #pragma unroll
            for (int j = 0; j < 7; ++j) {
                const int o = g_o + 16 * j;     // may be 100..111 (pad -> h=0)
                const float h = fmaxf(acc[n][j] + red[g * 29 + n * 7 + j]
                                      + bl_lds[o], 0.0f);
                a_lds[node_l * STR + o] = h;
            }
        }
    }
    __syncthreads();

    // ---- classifier: 1 thread = (node, 2 classes)
    {
        const int node_l = tid >> 3;          // 0..63
        const int q = tid & 7;                // classes 2q, 2q+1
        float o0 = bc_lds[2 * q], o1 = bc_lds[2 * q + 1];
        const float* hP = a_lds + node_l * STR;
        const float* w0 = wc_lds + (2 * q) * 100;
        const float* w1 = wc_lds + (2 * q + 1) * 100;
        for (int o = 0; o < 100; o += 4) {
            const float4 h4 = *reinterpret_cast<const float4*>(hP + o);
            const float4 a = *reinterpret_cast<const float4*>(w0 + o);
            const float4 b = *reinterpret_cast<const float4*>(w1 + o);
            o0 += h4.x * a.x + h4.y * a.y + h4.z * a.z + h4.w * a.w;
            o1 += h4.x * b.x + h4.y * b.y + h4.z * b.z + h4.w * b.w;
        }
        const int node = node0 + node_l;
        if (node < N_NODES)
            *reinterpret_cast<float2*>(out + (long)node * N_CLS + 2 * q) =
                make_float2(o0, o1);
    }
}

extern "C" void kernel_launch(void* const* d_in, const int* in_sizes, int n_in,
                              void* d_out, int out_size, void* d_ws, size_t ws_size,
                              hipStream_t stream) {
    const float* x  = (const float*)d_in[0];
    const int*   ei = (const int*)d_in[1];
    const float* Wl = (const float*)d_in[2];
    const float* bl = (const float*)d_in[3];
    const float* Wr = (const float*)d_in[4];
    const float* Wc = (const float*)d_in[5];
    const float* bc = (const float*)d_in[6];
    float* out = (float*)d_out;

    // ws layout (ints): cnt[N], rowptr[N+4], wofs[N], esrc[E], bsum[128],
    // boffs[128], then mean[N*100] f32 (offset 1,100,260 ints = 4,401,040 B, 16B-aligned)
    int* cnt    = (int*)d_ws;
    int* rowptr = cnt + N_NODES;
    int* wofs   = rowptr + N_NODES + 4;
    int* esrc   = wofs + N_NODES;
    int* bsum   = esrc + N_EDGES;
    int* boffs  = bsum + 128;
    float* mean = (float*)(boffs + 128);

    hipMemsetAsync(cnt, 0, N_NODES * sizeof(int), stream);

    hist_k<<<(N_EDGES + 255) / 256, 256, 0, stream>>>(ei, cnt);
    scan_a<<<SNBLK, 256, 0, stream>>>(cnt, bsum);
    scan_b<<<1, 128, 0, stream>>>(bsum, boffs, rowptr);
    scan_c<<<SNBLK, 256, 0, stream>>>(cnt, boffs, rowptr, wofs);
    fill_csr<<<(N_EDGES + 255) / 256, 256, 0, stream>>>(ei, wofs, esrc);
    gather_mean<<<(N_NODES + 7) / 8, 256, 0, stream>>>(x, rowptr, esrc, mean);

    sage_node<<<(N_NODES + TN - 1) / TN, 512, 0, stream>>>(
        x, mean, Wl, bl, Wr, Wc, bc, out);
}

// Round 10
// 277.689 us; speedup vs baseline: 15.5765x; 1.4922x over previous
//
#include <hip/hip_runtime.h>
#include <hip/hip_bf16.h>
#include <hip/hip_fp16.h>

#define N_NODES 100000
#define N_EDGES 800000
#define D_IN 100
#define D_HID 100
#define N_CLS 16

#define TN 64        // nodes per block in node kernel
#define SK 232       // padded f16 K-stride in LDS/w16 (116 words%32=20 -> ~2-way max)
#define AK 200       // amx global K-stride (f16), no pad
#define SCHUNK 1024  // scan: elements per block
#define SNBLK 98     // ceil(100000/1024)

typedef _Float16 f16x8 __attribute__((ext_vector_type(8)));
typedef _Float16 f16x4 __attribute__((ext_vector_type(4)));
typedef float f32x4 __attribute__((ext_vector_type(4)));

// ---------------- Kernel 1: degree histogram (int atomics) ------------------
__global__ __launch_bounds__(256) void hist_k(const int* __restrict__ ei,
                                              int* __restrict__ cnt)
{
    const int e = blockIdx.x * 256 + threadIdx.x;
    if (e < N_EDGES) atomicAdd(&cnt[ei[N_EDGES + e]], 1);
}

// ---------------- Scan pass A: per-block chunk sums -------------------------
__global__ __launch_bounds__(256) void scan_a(const int* __restrict__ cnt,
                                              int* __restrict__ bsum)
{
    __shared__ int red[256];
    const int t = threadIdx.x;
    const int base = blockIdx.x * SCHUNK + t * 4;
    int s = 0;
    if (base + 3 < N_NODES) {
        const int4 v = *reinterpret_cast<const int4*>(cnt + base);
        s = v.x + v.y + v.z + v.w;
    } else {
        for (int i = 0; i < 4; ++i)
            if (base + i < N_NODES) s += cnt[base + i];
    }
    red[t] = s;
    __syncthreads();
    for (int d = 128; d > 0; d >>= 1) {
        if (t < d) red[t] += red[t + d];
        __syncthreads();
    }
    if (t == 0) bsum[blockIdx.x] = red[0];
}

// ---------------- Scan pass B: scan the 98 block sums (tiny) ----------------
__global__ __launch_bounds__(128) void scan_b(const int* __restrict__ bsum,
                                              int* __restrict__ boffs)
{
    __shared__ int s[128];
    const int t = threadIdx.x;
    const int v = (t < SNBLK) ? bsum[t] : 0;
    s[t] = v;
    __syncthreads();
    for (int d = 1; d < 128; d <<= 1) {
        const int a = s[t];
        const int add = (t >= d) ? s[t - d] : 0;
        __syncthreads();
        s[t] = a + add;
        __syncthreads();
    }
    if (t < SNBLK) boffs[t] = s[t] - v;     // exclusive
}

// ---------------- Scan pass C: block-local scan + global offset -------------
__global__ __launch_bounds__(256) void scan_c(const int* __restrict__ cnt,
                                              const int* __restrict__ boffs,
                                              int* __restrict__ wofs)
{
    __shared__ int red[256];
    const int t = threadIdx.x;
    const int base = blockIdx.x * SCHUNK + t * 4;
    int c0 = 0, c1 = 0, c2 = 0, c3 = 0;
    if (base + 3 < N_NODES) {
        const int4 v = *reinterpret_cast<const int4*>(cnt + base);
        c0 = v.x; c1 = v.y; c2 = v.z; c3 = v.w;
    } else {
        if (base + 0 < N_NODES) c0 = cnt[base + 0];
        if (base + 1 < N_NODES) c1 = cnt[base + 1];
        if (base + 2 < N_NODES) c2 = cnt[base + 2];
        if (base + 3 < N_NODES) c3 = cnt[base + 3];
    }
    const int s = c0 + c1 + c2 + c3;
    red[t] = s;
    __syncthreads();
    for (int d = 1; d < 256; d <<= 1) {
        const int a = red[t];
        const int add = (t >= d) ? red[t - d] : 0;
        __syncthreads();
        red[t] = a + add;
        __syncthreads();
    }
    int prefix = boffs[blockIdx.x] + red[t] - s;
    const int c[4] = {c0, c1, c2, c3};
    for (int i = 0; i < 4; ++i) {
        const int idx = base + i;
        if (idx < N_NODES) {
            wofs[idx] = prefix;
            prefix += c[i];
        }
    }
}

// ---------------- Kernel 3: fill CSR adjacency ------------------------------
// After this kernel: wofs[n] == inclusive prefix == row-end of node n.
__global__ __launch_bounds__(256) void fill_csr(const int* __restrict__ ei,
                                                int* __restrict__ wofs,
                                                int* __restrict__ esrc)
{
    const int e = blockIdx.x * 256 + threadIdx.x;
    if (e >= N_EDGES) return;
    const int src = ei[e];
    const int dst = ei[N_EDGES + e];
    const int pos = atomicAdd(&wofs[dst], 1);
    esrc[pos] = src;
}

// ---------------- Kernel 4a: pack weights to f16 panel [128][SK] ------------
// row o: cols 0..99 = Wl[o][:], 100..199 = Wr[o][:], 200..231 = 0; rows>=100 = 0
__global__ __launch_bounds__(256) void cvt_w16(const float* __restrict__ Wl,
                                               const float* __restrict__ Wr,
                                               _Float16* __restrict__ w16)
{
    const int idx = blockIdx.x * 256 + threadIdx.x;   // o*58 + s
    if (idx >= 128 * 58) return;
    const int o = idx / 58, s = idx - o * 58;
    const int k0 = s * 4;
    float4 v = make_float4(0.f, 0.f, 0.f, 0.f);
    if (o < 100) {
        if (s < 25)       v = *reinterpret_cast<const float4*>(Wl + o * 100 + k0);
        else if (s < 50)  v = *reinterpret_cast<const float4*>(Wr + o * 100 + (k0 - 100));
    }
    f16x4 h = { (_Float16)v.x, (_Float16)v.y, (_Float16)v.z, (_Float16)v.w };
    *reinterpret_cast<f16x4*>(w16 + o * SK + k0) = h;
}

// ---------------- Kernel 4b: pack x to f16 into amx cols 100..199 -----------
__global__ __launch_bounds__(256) void cvt_x16(const float* __restrict__ x,
                                               _Float16* __restrict__ amx)
{
    const int idx = blockIdx.x * 256 + threadIdx.x;   // n*25 + s
    if (idx >= N_NODES * 25) return;
    const int n = idx / 25, s = idx - n * 25;
    const float4 v = *reinterpret_cast<const float4*>(x + (long)n * D_IN + s * 4);
    f16x4 h = { (_Float16)v.x, (_Float16)v.y, (_Float16)v.z, (_Float16)v.w };
    *reinterpret_cast<f16x4*>(amx + (long)n * AK + 100 + s * 4) = h;
}

// ---------------- Kernel 5: gather-mean (f16 in/out) ------------------------
// Row bounds from post-fill wofs: r0 = wofs[node-1] (0 for node 0), r1 = wofs[node].
__global__ __launch_bounds__(256) void gather_mean(
    const int* __restrict__ wofs, const int* __restrict__ esrc,
    _Float16* __restrict__ amx)
{
    const int node = blockIdx.x * 8 + (threadIdx.x >> 5);
    if (node >= N_NODES) return;
    const int l = threadIdx.x & 31;
    const int r0 = (node == 0) ? 0 : wofs[node - 1];
    const int r1 = wofs[node];
    const int deg = r1 - r0;

    float4 acc = make_float4(0.f, 0.f, 0.f, 0.f);
    for (int base = 0; base < deg; base += 32) {
        int s = 0;
        if (base + l < deg) s = esrc[r0 + base + l];      // coalesced
        const int rem = deg - base;
        const int m = rem < 32 ? rem : 32;
        for (int j = 0; j < m; ++j) {
            const int src = __shfl(s, j, 32);             // register broadcast
            if (l < 25) {
                const f16x4 v = *reinterpret_cast<const f16x4*>(
                    amx + (long)src * AK + 100 + l * 4);  // x16 half of amx
                acc.x += (float)v[0]; acc.y += (float)v[1];
                acc.z += (float)v[2]; acc.w += (float)v[3];
            }
        }
    }
    if (l < 25) {
        const float inv = 1.0f / fmaxf((float)deg, 1.0f);
        f16x4 h = { (_Float16)(acc.x * inv), (_Float16)(acc.y * inv),
                    (_Float16)(acc.z * inv), (_Float16)(acc.w * inv) };
        *reinterpret_cast<f16x4*>(amx + (long)node * AK + l * 4) = h;
    }
}

// ---------------- Kernel 6: MFMA node GEMM + classifier ---------------------
// out = relu(amx_f16 @ Wcat^T + bl) @ Wc^T + bc
// 512 thr = 8 waves (2M x 4N); wave tile 32 nodes x 32 outs; K=224 in 7 steps.
// All staging reg-staged (plain loads + ds_write) — no global_load_lds builtin.
__global__ __launch_bounds__(512, 1) void sage_node(
    const _Float16* __restrict__ amx, const _Float16* __restrict__ w16,
    const float* __restrict__ bl, const float* __restrict__ Wc,
    const float* __restrict__ bc, float* __restrict__ out)
{
    __shared__ __align__(16) _Float16 wS[128 * SK];   // 59392 B (later: h f32 [64][104])
    __shared__ __align__(16) _Float16 aS[TN * SK];    // 29696 B
    __shared__ float wcS[16 * 100];
    __shared__ float blS[128];
    __shared__ float bcS[16];

    const int tid = threadIdx.x;
    const int wid = tid >> 6;
    const int lane = tid & 63;
    const int node0 = blockIdx.x * TN;

    // ---- W panel: linear reg-staged copy, 128*29 = 3712 x 16B chunks
    for (int c = tid; c < 128 * 29; c += 512) {
        const f16x8 v = *reinterpret_cast<const f16x8*>(w16 + c * 8);
        *reinterpret_cast<f16x8*>(wS + c * 8) = v;
    }
    // ---- A tile: reg-staged, stride AK=200 -> SK=232 with zero K-pad.
    // 64 rows x 29 chunks of 16B: j<25 from global, j>=25 zero.
    {
        const f16x8 z = { (_Float16)0.f, (_Float16)0.f, (_Float16)0.f, (_Float16)0.f,
                          (_Float16)0.f, (_Float16)0.f, (_Float16)0.f, (_Float16)0.f };
        const _Float16* ga = amx + (size_t)node0 * AK;
        for (int c = tid; c < 64 * 29; c += 512) {
            const int row = c / 29, j = c - row * 29;
            f16x8 v = z;
            if (j < 25) v = *reinterpret_cast<const f16x8*>(ga + row * AK + j * 8);
            *reinterpret_cast<f16x8*>(aS + row * SK + j * 8) = v;
        }
    }
    for (int i = tid; i < 1600; i += 512) wcS[i] = Wc[i];
    if (tid < 128) blS[tid] = (tid < 100) ? bl[tid] : 0.0f;
    if (tid < 16)  bcS[tid] = bc[tid];
    __syncthreads();

    // ---- MFMA main loop
    const int wr = wid >> 2;            // 0..1 : node half (32 rows)
    const int wq = wid & 3;             // 0..3 : out quarter (32 cols)
    const int lrow = lane & 15;
    const int lk = (lane >> 4) * 8;     // f16 k-offset within 32-chunk

    f32x4 acc00 = {0.f, 0.f, 0.f, 0.f}, acc01 = acc00, acc10 = acc00, acc11 = acc00;
    const _Float16* aB = aS + (wr * 32 + lrow) * SK + lk;
    const _Float16* bB = wS + (wq * 32 + lrow) * SK + lk;

    #pragma unroll
    for (int ks = 0; ks < 7; ++ks) {
        const f16x8 a0 = *reinterpret_cast<const f16x8*>(aB + ks * 32);
        const f16x8 a1 = *reinterpret_cast<const f16x8*>(aB + 16 * SK + ks * 32);
        const f16x8 b0 = *reinterpret_cast<const f16x8*>(bB + ks * 32);
        const f16x8 b1 = *reinterpret_cast<const f16x8*>(bB + 16 * SK + ks * 32);
        acc00 = __builtin_amdgcn_mfma_f32_16x16x32_f16(a0, b0, acc00, 0, 0, 0);
        acc01 = __builtin_amdgcn_mfma_f32_16x16x32_f16(a0, b1, acc01, 0, 0, 0);
        acc10 = __builtin_amdgcn_mfma_f32_16x16x32_f16(a1, b0, acc10, 0, 0, 0);
        acc11 = __builtin_amdgcn_mfma_f32_16x16x32_f16(a1, b1, acc11, 0, 0, 0);
    }
    __syncthreads();   // all wS fragment reads complete; reuse as h

    // ---- h = relu(acc + bl) -> hS [64][104] f32 (26624 B, overlays wS)
    float* hS = reinterpret_cast<float*>(wS);
    const int crow = (lane >> 4) * 4;   // C layout: row=(lane>>4)*4+reg, col=lane&15
    const int ccol = lane & 15;
    #pragma unroll
    for (int mi = 0; mi < 2; ++mi) {
        #pragma unroll
        for (int ni = 0; ni < 2; ++ni) {
            const f32x4 a = (mi == 0) ? (ni == 0 ? acc00 : acc01)
                                      : (ni == 0 ? acc10 : acc11);
            const int o = wq * 32 + ni * 16 + ccol;
            #pragma unroll
            for (int r = 0; r < 4; ++r) {
                const int nl = wr * 32 + mi * 16 + crow + r;
                if (o < 104)
                    hS[nl * 104 + o] = fmaxf(a[r] + blS[o], 0.0f);
            }
        }
    }
    __syncthreads();

    // ---- classifier: 1 thread = (node, 2 classes)
    {
        const int nl = tid >> 3;             // 0..63
        const int q = tid & 7;               // classes 2q, 2q+1
        float o0 = bcS[2 * q], o1 = bcS[2 * q + 1];
        const float* hP = hS + nl * 104;
        const float* w0 = wcS + (2 * q) * 100;
        const float* w1 = wcS + (2 * q + 1) * 100;
        for (int o = 0; o < 100; o += 4) {
            const float4 h4 = *reinterpret_cast<const float4*>(hP + o);
            const float4 a = *reinterpret_cast<const float4*>(w0 + o);
            const float4 b = *reinterpret_cast<const float4*>(w1 + o);
            o0 += h4.x * a.x + h4.y * a.y + h4.z * a.z + h4.w * a.w;
            o1 += h4.x * b.x + h4.y * b.y + h4.z * b.z + h4.w * b.w;
        }
        const int node = node0 + nl;
        if (node < N_NODES)
            *reinterpret_cast<float2*>(out + (long)node * N_CLS + 2 * q) =
                make_float2(o0, o1);
    }
}

extern "C" void kernel_launch(void* const* d_in, const int* in_sizes, int n_in,
                              void* d_out, int out_size, void* d_ws, size_t ws_size,
                              hipStream_t stream) {
    const float* x  = (const float*)d_in[0];
    const int*   ei = (const int*)d_in[1];
    const float* Wl = (const float*)d_in[2];
    const float* bl = (const float*)d_in[3];
    const float* Wr = (const float*)d_in[4];
    const float* Wc = (const float*)d_in[5];
    const float* bc = (const float*)d_in[6];
    float* out = (float*)d_out;

    // ws layout: ints cnt[N], wofs[N+4], esrc[E], bsum[128], boffs[128];
    // then w16 f16[128*SK]; then amx f16[100032*AK]. Total ~44.07 MB.
    int* cnt    = (int*)d_ws;
    int* wofs   = cnt + N_NODES;
    int* esrc   = wofs + N_NODES + 4;
    int* bsum   = esrc + N_EDGES;
    int* boffs  = bsum + 128;
    _Float16* w16 = (_Float16*)(boffs + 128);   // byte 4,001,040 (16B-aligned)
    _Float16* amx = w16 + 128 * SK;             // byte 4,060,432 (16B-aligned)

    hipMemsetAsync(cnt, 0, N_NODES * sizeof(int), stream);

    hist_k<<<(N_EDGES + 255) / 256, 256, 0, stream>>>(ei, cnt);
    scan_a<<<SNBLK, 256, 0, stream>>>(cnt, bsum);
    scan_b<<<1, 128, 0, stream>>>(bsum, boffs);
    scan_c<<<SNBLK, 256, 0, stream>>>(cnt, boffs, wofs);
    fill_csr<<<(N_EDGES + 255) / 256, 256, 0, stream>>>(ei, wofs, esrc);
    cvt_w16<<<(128 * 58 + 255) / 256, 256, 0, stream>>>(Wl, Wr, w16);
    cvt_x16<<<(N_NODES * 25 + 255) / 256, 256, 0, stream>>>(x, amx);
    gather_mean<<<(N_NODES + 7) / 8, 256, 0, stream>>>(wofs, esrc, amx);

    sage_node<<<(N_NODES + TN - 1) / TN, 512, 0, stream>>>(
        amx, w16, bl, Wc, bc, out);
}

// Round 11
// 240.793 us; speedup vs baseline: 17.9632x; 1.1532x over previous
//
#include <hip/hip_runtime.h>
#include <hip/hip_bf16.h>
#include <hip/hip_fp16.h>

#define N_NODES 100000
#define N_EDGES 800000
#define D_IN 100
#define D_HID 100
#define N_CLS 16

#define TN 64        // nodes per block in node kernel
#define SK 232       // padded f16 K-stride in LDS/w16
#define AK 200       // amx global K-stride (f16), no pad
#define SCHUNK 1024  // scan: elements per block
#define SNBLK 98     // ceil(100000/1024)

typedef _Float16 f16x8 __attribute__((ext_vector_type(8)));
typedef _Float16 f16x4 __attribute__((ext_vector_type(4)));
typedef float f32x4 __attribute__((ext_vector_type(4)));

// rank scratch: edge e -> ushort slot inside amx (rows 0..6249, cols 0..127),
// region fully overwritten later by cvt_x16 (cols 100..199) and gather (cols 0..99).
#define RANK_SLOT(e) (((e) >> 7) * AK + ((e) & 127))

// ---------------- Kernel 1: degree histogram + per-edge rank ---------------
__global__ __launch_bounds__(256) void hist_k(const int* __restrict__ ei,
                                              int* __restrict__ cnt,
                                              unsigned short* __restrict__ rank16)
{
    const int e = blockIdx.x * 256 + threadIdx.x;
    if (e < N_EDGES) {
        const int dst = ei[N_EDGES + e];
        const int r = atomicAdd(&cnt[dst], 1);
        rank16[RANK_SLOT(e)] = (unsigned short)r;   // coalesced 2B store
    }
}

// ---------------- Scan pass A: per-block chunk sums -------------------------
__global__ __launch_bounds__(256) void scan_a(const int* __restrict__ cnt,
                                              int* __restrict__ bsum)
{
    __shared__ int red[256];
    const int t = threadIdx.x;
    const int base = blockIdx.x * SCHUNK + t * 4;
    int s = 0;
    if (base + 3 < N_NODES) {
        const int4 v = *reinterpret_cast<const int4*>(cnt + base);
        s = v.x + v.y + v.z + v.w;
    } else {
        for (int i = 0; i < 4; ++i)
            if (base + i < N_NODES) s += cnt[base + i];
    }
    red[t] = s;
    __syncthreads();
    for (int d = 128; d > 0; d >>= 1) {
        if (t < d) red[t] += red[t + d];
        __syncthreads();
    }
    if (t == 0) bsum[blockIdx.x] = red[0];
}

// ---------------- Scan pass C: full scan (block sums scanned in-block) ------
// wofs[n] = exclusive prefix of cnt; wofs[N_NODES] = N_EDGES.
__global__ __launch_bounds__(256) void scan_c(const int* __restrict__ cnt,
                                              const int* __restrict__ bsum,
                                              int* __restrict__ wofs)
{
    __shared__ int red[256];
    __shared__ int sb[128];
    const int t = threadIdx.x;
    // in-block inclusive scan of the 98 chunk sums (every block redundantly)
    if (t < 128) sb[t] = (t < SNBLK) ? bsum[t] : 0;
    __syncthreads();
    for (int d = 1; d < 128; d <<= 1) {
        int a = 0;
        if (t < 128) { a = sb[t]; if (t >= d) a += sb[t - d]; }
        __syncthreads();
        if (t < 128) sb[t] = a;
        __syncthreads();
    }
    const int bofs = sb[blockIdx.x] - bsum[blockIdx.x];   // exclusive for this chunk
    if (blockIdx.x == 0 && t == 0) wofs[N_NODES] = sb[SNBLK - 1];

    const int base = blockIdx.x * SCHUNK + t * 4;
    int c0 = 0, c1 = 0, c2 = 0, c3 = 0;
    if (base + 3 < N_NODES) {
        const int4 v = *reinterpret_cast<const int4*>(cnt + base);
        c0 = v.x; c1 = v.y; c2 = v.z; c3 = v.w;
    } else {
        if (base + 0 < N_NODES) c0 = cnt[base + 0];
        if (base + 1 < N_NODES) c1 = cnt[base + 1];
        if (base + 2 < N_NODES) c2 = cnt[base + 2];
        if (base + 3 < N_NODES) c3 = cnt[base + 3];
    }
    const int s = c0 + c1 + c2 + c3;
    red[t] = s;
    __syncthreads();
    for (int d = 1; d < 256; d <<= 1) {
        const int a = red[t];
        const int add = (t >= d) ? red[t - d] : 0;
        __syncthreads();
        red[t] = a + add;
        __syncthreads();
    }
    int prefix = bofs + red[t] - s;
    const int c[4] = {c0, c1, c2, c3};
    for (int i = 0; i < 4; ++i) {
        const int idx = base + i;
        if (idx < N_NODES) {
            wofs[idx] = prefix;
            prefix += c[i];
        }
    }
}

// ---------------- Kernel 3: fill CSR (atomic-free permutation) --------------
__global__ __launch_bounds__(256) void fill_csr(const int* __restrict__ ei,
                                                const int* __restrict__ wofs,
                                                const unsigned short* __restrict__ rank16,
                                                int* __restrict__ esrc)
{
    const int e = blockIdx.x * 256 + threadIdx.x;
    if (e >= N_EDGES) return;
    const int src = ei[e];
    const int dst = ei[N_EDGES + e];
    const int pos = wofs[dst] + (int)rank16[RANK_SLOT(e)];
    esrc[pos] = src;
}

// ---------------- Kernel 4a: pack weights to f16 panel [128][SK] ------------
__global__ __launch_bounds__(256) void cvt_w16(const float* __restrict__ Wl,
                                               const float* __restrict__ Wr,
                                               _Float16* __restrict__ w16)
{
    const int idx = blockIdx.x * 256 + threadIdx.x;   // o*58 + s
    if (idx >= 128 * 58) return;
    const int o = idx / 58, s = idx - o * 58;
    const int k0 = s * 4;
    float4 v = make_float4(0.f, 0.f, 0.f, 0.f);
    if (o < 100) {
        if (s < 25)       v = *reinterpret_cast<const float4*>(Wl + o * 100 + k0);
        else if (s < 50)  v = *reinterpret_cast<const float4*>(Wr + o * 100 + (k0 - 100));
    }
    f16x4 h = { (_Float16)v.x, (_Float16)v.y, (_Float16)v.z, (_Float16)v.w };
    *reinterpret_cast<f16x4*>(w16 + o * SK + k0) = h;
}

// ---------------- Kernel 4b: pack x to f16 into amx cols 100..199 -----------
// Runs AFTER fill_csr (overwrites the rank scratch region).
__global__ __launch_bounds__(256) void cvt_x16(const float* __restrict__ x,
                                               _Float16* __restrict__ amx)
{
    const int idx = blockIdx.x * 256 + threadIdx.x;   // n*25 + s
    if (idx >= N_NODES * 25) return;
    const int n = idx / 25, s = idx - n * 25;
    const float4 v = *reinterpret_cast<const float4*>(x + (long)n * D_IN + s * 4);
    f16x4 h = { (_Float16)v.x, (_Float16)v.y, (_Float16)v.z, (_Float16)v.w };
    *reinterpret_cast<f16x4*>(amx + (long)n * AK + 100 + s * 4) = h;
}

// ---------------- Kernel 5: gather-mean (f16 in/out) ------------------------
// wofs is clean exclusive prefix: r0 = wofs[node], r1 = wofs[node+1].
__global__ __launch_bounds__(256) void gather_mean(
    const int* __restrict__ wofs, const int* __restrict__ esrc,
    _Float16* __restrict__ amx)
{
    const int node = blockIdx.x * 8 + (threadIdx.x >> 5);
    if (node >= N_NODES) return;
    const int l = threadIdx.x & 31;
    const int r0 = wofs[node];
    const int r1 = wofs[node + 1];
    const int deg = r1 - r0;

    float4 acc = make_float4(0.f, 0.f, 0.f, 0.f);
    for (int base = 0; base < deg; base += 32) {
        int s = 0;
        if (base + l < deg) s = esrc[r0 + base + l];      // coalesced
        const int rem = deg - base;
        const int m = rem < 32 ? rem : 32;
        for (int j = 0; j < m; ++j) {
            const int src = __shfl(s, j, 32);             // register broadcast
            if (l < 25) {
                const f16x4 v = *reinterpret_cast<const f16x4*>(
                    amx + (long)src * AK + 100 + l * 4);  // x16 half of amx
                acc.x += (float)v[0]; acc.y += (float)v[1];
                acc.z += (float)v[2]; acc.w += (float)v[3];
            }
        }
    }
    if (l < 25) {
        const float inv = 1.0f / fmaxf((float)deg, 1.0f);
        f16x4 h = { (_Float16)(acc.x * inv), (_Float16)(acc.y * inv),
                    (_Float16)(acc.z * inv), (_Float16)(acc.w * inv) };
        *reinterpret_cast<f16x4*>(amx + (long)node * AK + l * 4) = h;
    }
}

// ---------------- Kernel 6: MFMA node GEMM + classifier ---------------------
// out = relu(amx_f16 @ Wcat^T + bl) @ Wc^T + bc
// 512 thr = 8 waves (2M x 4N); wave tile 32 nodes x 32 outs; K=224 in 7 steps.
__global__ __launch_bounds__(512, 1) void sage_node(
    const _Float16* __restrict__ amx, const _Float16* __restrict__ w16,
    const float* __restrict__ bl, const float* __restrict__ Wc,
    const float* __restrict__ bc, float* __restrict__ out)
{
    __shared__ __align__(16) _Float16 wS[128 * SK];   // 59392 B (later: h f32 [64][104])
    __shared__ __align__(16) _Float16 aS[TN * SK];    // 29696 B
    __shared__ float wcS[16 * 100];
    __shared__ float blS[128];
    __shared__ float bcS[16];

    const int tid = threadIdx.x;
    const int wid = tid >> 6;
    const int lane = tid & 63;
    const int node0 = blockIdx.x * TN;

    // ---- W panel: linear reg-staged copy, 128*29 = 3712 x 16B chunks
    for (int c = tid; c < 128 * 29; c += 512) {
        const f16x8 v = *reinterpret_cast<const f16x8*>(w16 + c * 8);
        *reinterpret_cast<f16x8*>(wS + c * 8) = v;
    }
    // ---- A tile: reg-staged, stride AK=200 -> SK=232 with zero K-pad.
    {
        const f16x8 z = { (_Float16)0.f, (_Float16)0.f, (_Float16)0.f, (_Float16)0.f,
                          (_Float16)0.f, (_Float16)0.f, (_Float16)0.f, (_Float16)0.f };
        const _Float16* ga = amx + (size_t)node0 * AK;
        for (int c = tid; c < 64 * 29; c += 512) {
            const int row = c / 29, j = c - row * 29;
            f16x8 v = z;
            if (j < 25) v = *reinterpret_cast<const f16x8*>(ga + row * AK + j * 8);
            *reinterpret_cast<f16x8*>(aS + row * SK + j * 8) = v;
        }
    }
    for (int i = tid; i < 1600; i += 512) wcS[i] = Wc[i];
    if (tid < 128) blS[tid] = (tid < 100) ? bl[tid] : 0.0f;
    if (tid < 16)  bcS[tid] = bc[tid];
    __syncthreads();

    // ---- MFMA main loop
    const int wr = wid >> 2;            // 0..1 : node half (32 rows)
    const int wq = wid & 3;             // 0..3 : out quarter (32 cols)
    const int lrow = lane & 15;
    const int lk = (lane >> 4) * 8;     // f16 k-offset within 32-chunk

    f32x4 acc00 = {0.f, 0.f, 0.f, 0.f}, acc01 = acc00, acc10 = acc00, acc11 = acc00;
    const _Float16* aB = aS + (wr * 32 + lrow) * SK + lk;
    const _Float16* bB = wS + (wq * 32 + lrow) * SK + lk;

    #pragma unroll
    for (int ks = 0; ks < 7; ++ks) {
        const f16x8 a0 = *reinterpret_cast<const f16x8*>(aB + ks * 32);
        const f16x8 a1 = *reinterpret_cast<const f16x8*>(aB + 16 * SK + ks * 32);
        const f16x8 b0 = *reinterpret_cast<const f16x8*>(bB + ks * 32);
        const f16x8 b1 = *reinterpret_cast<const f16x8*>(bB + 16 * SK + ks * 32);
        acc00 = __builtin_amdgcn_mfma_f32_16x16x32_f16(a0, b0, acc00, 0, 0, 0);
        acc01 = __builtin_amdgcn_mfma_f32_16x16x32_f16(a0, b1, acc01, 0, 0, 0);
        acc10 = __builtin_amdgcn_mfma_f32_16x16x32_f16(a1, b0, acc10, 0, 0, 0);
        acc11 = __builtin_amdgcn_mfma_f32_16x16x32_f16(a1, b1, acc11, 0, 0, 0);
    }
    __syncthreads();   // all wS fragment reads complete; reuse as h

    // ---- h = relu(acc + bl) -> hS [64][104] f32 (26624 B, overlays wS)
    float* hS = reinterpret_cast<float*>(wS);
    const int crow = (lane >> 4) * 4;   // C layout: row=(lane>>4)*4+reg, col=lane&15
    const int ccol = lane & 15;
    #pragma unroll
    for (int mi = 0; mi < 2; ++mi) {
        #pragma unroll
        for (int ni = 0; ni < 2; ++ni) {
            const f32x4 a = (mi == 0) ? (ni == 0 ? acc00 : acc01)
                                      : (ni == 0 ? acc10 : acc11);
            const int o = wq * 32 + ni * 16 + ccol;
            #pragma unroll
            for (int r = 0; r < 4; ++r) {
                const int nl = wr * 32 + mi * 16 + crow + r;
                if (o < 104)
                    hS[nl * 104 + o] = fmaxf(a[r] + blS[o], 0.0f);
            }
        }
    }
    __syncthreads();

    // ---- classifier: 1 thread = (node, 2 classes)
    {
        const int nl = tid >> 3;             // 0..63
        const int q = tid & 7;               // classes 2q, 2q+1
        float o0 = bcS[2 * q], o1 = bcS[2 * q + 1];
        const float* hP = hS + nl * 104;
        const float* w0 = wcS + (2 * q) * 100;
        const float* w1 = wcS + (2 * q + 1) * 100;
        for (int o = 0; o < 100; o += 4) {
            const float4 h4 = *reinterpret_cast<const float4*>(hP + o);
            const float4 a = *reinterpret_cast<const float4*>(w0 + o);
            const float4 b = *reinterpret_cast<const float4*>(w1 + o);
            o0 += h4.x * a.x + h4.y * a.y + h4.z * a.z + h4.w * a.w;
            o1 += h4.x * b.x + h4.y * b.y + h4.z * b.z + h4.w * b.w;
        }
        const int node = node0 + nl;
        if (node < N_NODES)
            *reinterpret_cast<float2*>(out + (long)node * N_CLS + 2 * q) =
                make_float2(o0, o1);
    }
}

extern "C" void kernel_launch(void* const* d_in, const int* in_sizes, int n_in,
                              void* d_out, int out_size, void* d_ws, size_t ws_size,
                              hipStream_t stream) {
    const float* x  = (const float*)d_in[0];
    const int*   ei = (const int*)d_in[1];
    const float* Wl = (const float*)d_in[2];
    const float* bl = (const float*)d_in[3];
    const float* Wr = (const float*)d_in[4];
    const float* Wc = (const float*)d_in[5];
    const float* bc = (const float*)d_in[6];
    float* out = (float*)d_out;

    // ws layout: ints cnt[N], wofs[N+4], esrc[E], bsum[128];
    // then w16 f16[128*SK]; then amx f16[100032*AK]. Total ~44.07 MB.
    int* cnt    = (int*)d_ws;
    int* wofs   = cnt + N_NODES;
    int* esrc   = wofs + N_NODES + 4;
    int* bsum   = esrc + N_EDGES;
    _Float16* w16 = (_Float16*)(bsum + 128);    // 16B-aligned
    _Float16* amx = w16 + 128 * SK;             // 16B-aligned
    unsigned short* rank16 = (unsigned short*)amx;   // scratch inside amx

    hipMemsetAsync(cnt, 0, N_NODES * sizeof(int), stream);

    hist_k<<<(N_EDGES + 255) / 256, 256, 0, stream>>>(ei, cnt, rank16);
    scan_a<<<SNBLK, 256, 0, stream>>>(cnt, bsum);
    scan_c<<<SNBLK, 256, 0, stream>>>(cnt, bsum, wofs);
    fill_csr<<<(N_EDGES + 255) / 256, 256, 0, stream>>>(ei, wofs, rank16, esrc);
    cvt_w16<<<(128 * 58 + 255) / 256, 256, 0, stream>>>(Wl, Wr, w16);
    cvt_x16<<<(N_NODES * 25 + 255) / 256, 256, 0, stream>>>(x, amx);
    gather_mean<<<(N_NODES + 7) / 8, 256, 0, stream>>>(wofs, esrc, amx);

    sage_node<<<(N_NODES + TN - 1) / TN, 512, 0, stream>>>(
        amx, w16, bl, Wc, bc, out);
}

// Round 15
// 225.623 us; speedup vs baseline: 19.1710x; 1.0672x over previous
//
#include <hip/hip_runtime.h>
#include <hip/hip_bf16.h>
#include <hip/hip_fp16.h>

#define N_NODES 100000
#define N_EDGES 800000
#define D_IN 100
#define D_HID 100
#define N_CLS 16

#define TN 128       // nodes per block in node kernel
#define SK 232       // padded f16 K-stride in LDS/w16
#define AK 200       // amx global K-stride (f16), no pad
#define HSTR 136     // h f16 LDS stride (68 words % 32 = 4 -> 2-way max)
#define SCHUNK 1024  // scan: elements per block
#define SNBLK 98     // ceil(100000/1024)
#define FBLK 3125    // fill blocks (800000/256)

typedef _Float16 f16x8 __attribute__((ext_vector_type(8)));
typedef _Float16 f16x4 __attribute__((ext_vector_type(4)));
typedef float f32x4 __attribute__((ext_vector_type(4)));

// rank scratch inside amx: edge e -> rows 0..7999, cols 0..99 (ushort).
// Disjoint from cvt_x16's cols 100..199 -> fill & cvtX can co-run.
#define RANK_SLOT(e) (((e) / 100) * AK + ((e) % 100))

// ---------------- Kernel 1: degree histogram + per-edge rank ---------------
__global__ __launch_bounds__(256) void hist_k(const int* __restrict__ ei,
                                              int* __restrict__ cnt,
                                              unsigned short* __restrict__ rank16)
{
    const int e = blockIdx.x * 256 + threadIdx.x;
    if (e < N_EDGES) {
        const int dst = ei[N_EDGES + e];
        const int r = atomicAdd(&cnt[dst], 1);
        rank16[RANK_SLOT(e)] = (unsigned short)r;
    }
}

// ---------------- Kernel 2: scan pass A  ||  pack weights to f16 ------------
__global__ __launch_bounds__(256) void scanA_cvtW(
    const int* __restrict__ cnt, int* __restrict__ bsum,
    const float* __restrict__ Wl, const float* __restrict__ Wr,
    _Float16* __restrict__ w16)
{
    const int t = threadIdx.x;
    if (blockIdx.x < SNBLK) {
        __shared__ int red[256];
        const int base = blockIdx.x * SCHUNK + t * 4;
        int s = 0;
        if (base + 3 < N_NODES) {
            const int4 v = *reinterpret_cast<const int4*>(cnt + base);
            s = v.x + v.y + v.z + v.w;
        } else {
            for (int i = 0; i < 4; ++i)
                if (base + i < N_NODES) s += cnt[base + i];
        }
        red[t] = s;
        __syncthreads();
        for (int d = 128; d > 0; d >>= 1) {
            if (t < d) red[t] += red[t + d];
            __syncthreads();
        }
        if (t == 0) bsum[blockIdx.x] = red[0];
    } else {
        // w16 row o: cols 0..99 = Wl[o], 100..199 = Wr[o], 200..231 = 0; rows>=100 = 0
        const int idx = (blockIdx.x - SNBLK) * 256 + t;   // o*58 + s
        if (idx >= 128 * 58) return;
        const int o = idx / 58, s = idx - o * 58;
        const int k0 = s * 4;
        float4 v = make_float4(0.f, 0.f, 0.f, 0.f);
        if (o < 100) {
            if (s < 25)       v = *reinterpret_cast<const float4*>(Wl + o * 100 + k0);
            else if (s < 50)  v = *reinterpret_cast<const float4*>(Wr + o * 100 + (k0 - 100));
        }
        f16x4 h = { (_Float16)v.x, (_Float16)v.y, (_Float16)v.z, (_Float16)v.w };
        *reinterpret_cast<f16x4*>(w16 + o * SK + k0) = h;
    }
}

// ---------------- Kernel 3: scan pass C (full scan, block sums in-block) ----
__global__ __launch_bounds__(256) void scan_c(const int* __restrict__ cnt,
                                              const int* __restrict__ bsum,
                                              int* __restrict__ wofs)
{
    __shared__ int red[256];
    __shared__ int sb[128];
    const int t = threadIdx.x;
    if (t < 128) sb[t] = (t < SNBLK) ? bsum[t] : 0;
    __syncthreads();
    for (int d = 1; d < 128; d <<= 1) {
        int a = 0;
        if (t < 128) { a = sb[t]; if (t >= d) a += sb[t - d]; }
        __syncthreads();
        if (t < 128) sb[t] = a;
        __syncthreads();
    }
    const int bofs = sb[blockIdx.x] - bsum[blockIdx.x];
    if (blockIdx.x == 0 && t == 0) wofs[N_NODES] = sb[SNBLK - 1];

    const int base = blockIdx.x * SCHUNK + t * 4;
    int c0 = 0, c1 = 0, c2 = 0, c3 = 0;
    if (base + 3 < N_NODES) {
        const int4 v = *reinterpret_cast<const int4*>(cnt + base);
        c0 = v.x; c1 = v.y; c2 = v.z; c3 = v.w;
    } else {
        if (base + 0 < N_NODES) c0 = cnt[base + 0];
        if (base + 1 < N_NODES) c1 = cnt[base + 1];
        if (base + 2 < N_NODES) c2 = cnt[base + 2];
        if (base + 3 < N_NODES) c3 = cnt[base + 3];
    }
    const int s = c0 + c1 + c2 + c3;
    red[t] = s;
    __syncthreads();
    for (int d = 1; d < 256; d <<= 1) {
        const int a = red[t];
        const int add = (t >= d) ? red[t - d] : 0;
        __syncthreads();
        red[t] = a + add;
        __syncthreads();
    }
    int prefix = bofs + red[t] - s;
    const int c[4] = {c0, c1, c2, c3};
    for (int i = 0; i < 4; ++i) {
        const int idx = base + i;
        if (idx < N_NODES) {
            wofs[idx] = prefix;
            prefix += c[i];
        }
    }
}

// ---------------- Kernel 4: fill CSR (atomic-free)  ||  pack x to f16 -------
__global__ __launch_bounds__(256) void fill_cvtX(
    const int* __restrict__ ei, const int* __restrict__ wofs,
    const unsigned short* __restrict__ rank16, int* __restrict__ esrc,
    const float* __restrict__ x, _Float16* __restrict__ amx)
{
    const int t = threadIdx.x;
    if (blockIdx.x < FBLK) {
        const int e = blockIdx.x * 256 + t;
        if (e >= N_EDGES) return;
        const int src = ei[e];
        const int dst = ei[N_EDGES + e];
        const int pos = wofs[dst] + (int)rank16[RANK_SLOT(e)];
        esrc[pos] = src;
    } else {
        const int idx = (blockIdx.x - FBLK) * 256 + t;   // n*25 + s
        if (idx >= N_NODES * 25) return;
        const int n = idx / 25, s = idx - n * 25;
        const float4 v = *reinterpret_cast<const float4*>(x + (long)n * D_IN + s * 4);
        f16x4 h = { (_Float16)v.x, (_Float16)v.y, (_Float16)v.z, (_Float16)v.w };
        *reinterpret_cast<f16x4*>(amx + (long)n * AK + 100 + s * 4) = h;
    }
}

// ---------------- Kernel 5: gather-mean (f16 in/out) ------------------------
__global__ __launch_bounds__(256) void gather_mean(
    const int* __restrict__ wofs, const int* __restrict__ esrc,
    _Float16* __restrict__ amx)
{
    const int node = blockIdx.x * 8 + (threadIdx.x >> 5);
    if (node >= N_NODES) return;
    const int l = threadIdx.x & 31;
    const int r0 = wofs[node];
    const int r1 = wofs[node + 1];
    const int deg = r1 - r0;

    float4 acc = make_float4(0.f, 0.f, 0.f, 0.f);
    for (int base = 0; base < deg; base += 32) {
        int s = 0;
        if (base + l < deg) s = esrc[r0 + base + l];      // coalesced
        const int rem = deg - base;
        const int m = rem < 32 ? rem : 32;
        for (int j = 0; j < m; ++j) {
            const int src = __shfl(s, j, 32);             // register broadcast
            if (l < 25) {
                const f16x4 v = *reinterpret_cast<const f16x4*>(
                    amx + (long)src * AK + 100 + l * 4);
                acc.x += (float)v[0]; acc.y += (float)v[1];
                acc.z += (float)v[2]; acc.w += (float)v[3];
            }
        }
    }
    if (l < 25) {
        const float inv = 1.0f / fmaxf((float)deg, 1.0f);
        f16x4 h = { (_Float16)(acc.x * inv), (_Float16)(acc.y * inv),
                    (_Float16)(acc.z * inv), (_Float16)(acc.w * inv) };
        *reinterpret_cast<f16x4*>(amx + (long)node * AK + l * 4) = h;
    }
}

// ---------------- Kernel 6: MFMA node GEMM + MFMA classifier ----------------
// h = relu(amx_f16 @ Wcat^T + bl);  out = h @ Wc^T + bc  (both via MFMA)
// 512 thr = 8 waves; main: wave tile 64 nodes x 32 outs, K=224 (7 ks).
// classifier: wave = one 16-node tile, K=128 (4 ks), h f16 overlays wS.
__global__ __launch_bounds__(512, 1) void sage_node(
    const _Float16* __restrict__ amx, const _Float16* __restrict__ w16,
    const float* __restrict__ bl, const float* __restrict__ Wc,
    const float* __restrict__ bc, float* __restrict__ out)
{
    __shared__ __align__(16) _Float16 wS[128 * SK];   // 59392 B; later h [128][HSTR]
    __shared__ __align__(16) _Float16 aS[TN * SK];    // 59392 B
    __shared__ __align__(16) _Float16 wc16[16 * HSTR];// 4352 B (cols 100..135 = 0)
    __shared__ float blS[128];
    __shared__ float bcS[16];

    const int tid = threadIdx.x;
    const int wid = tid >> 6;
    const int lane = tid & 63;
    const int node0 = blockIdx.x * TN;

    // ---- W panel: linear reg-staged copy, 128*29 x 16B
    for (int c = tid; c < 128 * 29; c += 512) {
        const f16x8 v = *reinterpret_cast<const f16x8*>(w16 + c * 8);
        *reinterpret_cast<f16x8*>(wS + c * 8) = v;
    }
    // ---- A tile: 128 rows x 29 chunks; j>=25 zero K-pad; row-guarded
    {
        const f16x8 z = { (_Float16)0.f, (_Float16)0.f, (_Float16)0.f, (_Float16)0.f,
                          (_Float16)0.f, (_Float16)0.f, (_Float16)0.f, (_Float16)0.f };
        for (int c = tid; c < TN * 29; c += 512) {
            const int row = c / 29, j = c - row * 29;
            f16x8 v = z;
            if (j < 25 && node0 + row < N_NODES)
                v = *reinterpret_cast<const f16x8*>(
                    amx + (long)(node0 + row) * AK + j * 8);
            *reinterpret_cast<f16x8*>(aS + row * SK + j * 8) = v;
        }
    }
    // ---- Wc -> f16 [16][HSTR], zero-padded K
    for (int i = tid; i < 16 * HSTR; i += 512) {
        const int cls = i / HSTR, k = i - cls * HSTR;
        wc16[i] = (k < 100) ? (_Float16)Wc[cls * 100 + k] : (_Float16)0.f;
    }
    if (tid < 128) blS[tid] = (tid < 100) ? bl[tid] : 0.0f;
    if (tid < 16)  bcS[tid] = bc[tid];
    __syncthreads();

    // ---- main MFMA: wave tile 64 nodes (wr) x 32 outs (wq)
    const int wr = wid >> 2;            // 0..1 : node half (64 rows)
    const int wq = wid & 3;             // 0..3 : out quarter (32 cols)
    const int lrow = lane & 15;
    const int lk = (lane >> 4) * 8;

    f32x4 acc[4][2];
    #pragma unroll
    for (int mi = 0; mi < 4; ++mi)
        #pragma unroll
        for (int ni = 0; ni < 2; ++ni) acc[mi][ni] = (f32x4){0.f, 0.f, 0.f, 0.f};

    const _Float16* aB = aS + (wr * 64 + lrow) * SK + lk;
    const _Float16* bB = wS + (wq * 32 + lrow) * SK + lk;

    #pragma unroll
    for (int ks = 0; ks < 7; ++ks) {
        const f16x8 b0 = *reinterpret_cast<const f16x8*>(bB + ks * 32);
        const f16x8 b1 = *reinterpret_cast<const f16x8*>(bB + 16 * SK + ks * 32);
        #pragma unroll
        for (int mi = 0; mi < 4; ++mi) {
            const f16x8 a = *reinterpret_cast<const f16x8*>(aB + mi * 16 * SK + ks * 32);
            acc[mi][0] = __builtin_amdgcn_mfma_f32_16x16x32_f16(a, b0, acc[mi][0], 0, 0, 0);
            acc[mi][1] = __builtin_amdgcn_mfma_f32_16x16x32_f16(a, b1, acc[mi][1], 0, 0, 0);
        }
    }
    __syncthreads();   // all wS reads done; reuse as h

    // ---- h = relu(acc + bl) -> hS f16 [128][HSTR] (34816 B, overlays wS)
    _Float16* hS = wS;
    const int crow = (lane >> 4) * 4;   // C layout: row=(lane>>4)*4+reg, col=lane&15
    const int ccol = lane & 15;
    #pragma unroll
    for (int mi = 0; mi < 4; ++mi) {
        #pragma unroll
        for (int ni = 0; ni < 2; ++ni) {
            const int o = wq * 32 + ni * 16 + ccol;        // 0..127 (>=100 -> h=0)
            #pragma unroll
            for (int r = 0; r < 4; ++r) {
                const int rowl = wr * 64 + mi * 16 + crow + r;
                hS[rowl * HSTR + o] = (_Float16)fmaxf(acc[mi][ni][r] + blS[o], 0.0f);
            }
        }
    }
    __syncthreads();

    // ---- classifier MFMA: wave wid owns 16-node tile; K=128 (cols>=100 zero)
    {
        const _Float16* aR = hS + (wid * 16 + lrow) * HSTR + lk;
        const _Float16* bR = wc16 + lrow * HSTR + lk;     // lrow = class
        f32x4 c4 = {0.f, 0.f, 0.f, 0.f};
        #pragma unroll
        for (int ks = 0; ks < 4; ++ks) {
            const f16x8 a = *reinterpret_cast<const f16x8*>(aR + ks * 32);
            const f16x8 b = *reinterpret_cast<const f16x8*>(bR + ks * 32);
            c4 = __builtin_amdgcn_mfma_f32_16x16x32_f16(a, b, c4, 0, 0, 0);
        }
        const float bcv = bcS[lane & 15];
        #pragma unroll
        for (int r = 0; r < 4; ++r) {
            const int node = node0 + wid * 16 + (lane >> 4) * 4 + r;
            if (node < N_NODES)
                out[(long)node * N_CLS + (lane & 15)] = c4[r] + bcv;
        }
    }
}

extern "C" void kernel_launch(void* const* d_in, const int* in_sizes, int n_in,
                              void* d_out, int out_size, void* d_ws, size_t ws_size,
                              hipStream_t stream) {
    const float* x  = (const float*)d_in[0];
    const int*   ei = (const int*)d_in[1];
    const float* Wl = (const float*)d_in[2];
    const float* bl = (const float*)d_in[3];
    const float* Wr = (const float*)d_in[4];
    const float* Wc = (const float*)d_in[5];
    const float* bc = (const float*)d_in[6];
    float* out = (float*)d_out;

    // ws: ints cnt[N], wofs[N+4], esrc[E], bsum[128]; w16 f16[128*SK]; amx f16[100032*AK]
    int* cnt    = (int*)d_ws;
    int* wofs   = cnt + N_NODES;
    int* esrc   = wofs + N_NODES + 4;
    int* bsum   = esrc + N_EDGES;
    _Float16* w16 = (_Float16*)(bsum + 128);    // 16B-aligned
    _Float16* amx = w16 + 128 * SK;             // 16B-aligned
    unsigned short* rank16 = (unsigned short*)amx;   // rows 0..7999, cols 0..99

    hipMemsetAsync(cnt, 0, N_NODES * sizeof(int), stream);

    hist_k<<<(N_EDGES + 255) / 256, 256, 0, stream>>>(ei, cnt, rank16);
    scanA_cvtW<<<SNBLK + 29, 256, 0, stream>>>(cnt, bsum, Wl, Wr, w16);
    scan_c<<<SNBLK, 256, 0, stream>>>(cnt, bsum, wofs);
    fill_cvtX<<<FBLK + (N_NODES * 25 + 255) / 256, 256, 0, stream>>>(
        ei, wofs, rank16, esrc, x, amx);
    gather_mean<<<(N_NODES + 7) / 8, 256, 0, stream>>>(wofs, esrc, amx);

    sage_node<<<(N_NODES + TN - 1) / TN, 512, 0, stream>>>(
        amx, w16, bl, Wc, bc, out);
}